// Round 1
// baseline (185.676 us; speedup 1.0000x reference)
//
#include <hip/hip_runtime.h>
#include <hip/hip_bf16.h>
#include <stdint.h>

// Problem constants (fixed by reference)
#define NB    8
#define NS    2048
#define NE    1024
#define NH    16
#define NDK   64
#define MTOK  (NB*NS)      // 16384 tokens

typedef __attribute__((ext_vector_type(8))) short bf16x8;
typedef __attribute__((ext_vector_type(4))) float f32x4;

// round-to-nearest-even f32 -> bf16 bits
__device__ __forceinline__ ushort f2bf(float f) {
  uint32_t u = __float_as_uint(f);
  u += 0x7FFFu + ((u >> 16) & 1u);
  return (ushort)(u >> 16);
}

__device__ __forceinline__ void gload16(const void* g, void* l) {
  __builtin_amdgcn_global_load_lds(
      (const __attribute__((address_space(1))) void*)g,
      (__attribute__((address_space(3))) void*)l, 16, 0, 0);
}

// ---------------- f32 -> bf16 cast (vectorized) ----------------
__global__ __launch_bounds__(256) void cvt_bf16(const float* __restrict__ in,
                                                ushort* __restrict__ out, int n4) {
  int stride = gridDim.x * blockDim.x;
  for (int j = blockIdx.x * blockDim.x + threadIdx.x; j < n4; j += stride) {
    float4 v = ((const float4*)in)[j];
    ushort4 o;
    o.x = f2bf(v.x); o.y = f2bf(v.y); o.z = f2bf(v.z); o.w = f2bf(v.w);
    ((ushort4*)out)[j] = o;
  }
}

// ---------------- bf16 GEMM: C[m,n] = sum_k A[m,k]*B[n,k] (f32 out) ----------------
// 128x128 tile, BK=32, 4 waves (2x2), 4x4 16x16x32 fragments per wave.
#define BM 128
#define BN 128
#define BK 32

__global__ __launch_bounds__(256) void gemm_bt(const ushort* __restrict__ A,
                                               const ushort* __restrict__ Bm,
                                               float* __restrict__ C,
                                               int M, int N, int K) {
  __shared__ ushort As[2][BM * BK];
  __shared__ ushort Bs[2][BN * BK];

  int tid  = threadIdx.x;
  int lane = tid & 63;
  int w    = tid >> 6;
  int wr   = w >> 1, wc = w & 1;
  int bc   = blockIdx.x, br = blockIdx.y;

  const ushort* Abase = A  + (size_t)(br * BM) * K;
  const ushort* Bbase = Bm + (size_t)(bc * BN) * K;

  int srow = lane >> 2;        // 0..15 (rows within a 1KB chunk)
  int skk  = (lane & 3) * 8;   // k-offset elems

  f32x4 zero = {0.f, 0.f, 0.f, 0.f};
  f32x4 acc[4][4];
#pragma unroll
  for (int m = 0; m < 4; ++m)
#pragma unroll
    for (int n = 0; n < 4; ++n) acc[m][n] = zero;

  int NKT = K / BK;
  int cur = 0;

  // prologue: stage tile 0 into buffer 0
#pragma unroll
  for (int j = 0; j < 2; ++j) {
    int c = w * 2 + j;                    // chunk 0..7, wave-uniform
    gload16(Abase + (size_t)(c * 16 + srow) * K + skk, &As[0][c * 512]);
    gload16(Bbase + (size_t)(c * 16 + srow) * K + skk, &Bs[0][c * 512]);
  }

  int fr = lane & 15;
  int fk = (lane >> 4) * 8;

  for (int kt = 0; kt < NKT; ++kt) {
    __syncthreads();  // stage(kt) complete (vmcnt drained), prev reads done
    if (kt + 1 < NKT) {
      int k0 = (kt + 1) * BK;
#pragma unroll
      for (int j = 0; j < 2; ++j) {
        int c = w * 2 + j;
        gload16(Abase + (size_t)(c * 16 + srow) * K + k0 + skk, &As[cur ^ 1][c * 512]);
        gload16(Bbase + (size_t)(c * 16 + srow) * K + k0 + skk, &Bs[cur ^ 1][c * 512]);
      }
    }
    bf16x8 af[4], bfr[4];
#pragma unroll
    for (int m = 0; m < 4; ++m)
      af[m] = *(const bf16x8*)&As[cur][(wr * 64 + m * 16 + fr) * BK + fk];
#pragma unroll
    for (int n = 0; n < 4; ++n)
      bfr[n] = *(const bf16x8*)&Bs[cur][(wc * 64 + n * 16 + fr) * BK + fk];
#pragma unroll
    for (int m = 0; m < 4; ++m)
#pragma unroll
      for (int n = 0; n < 4; ++n)
        acc[m][n] = __builtin_amdgcn_mfma_f32_16x16x32_bf16(af[m], bfr[n], acc[m][n], 0, 0, 0);
    cur ^= 1;
  }

  // epilogue: C/D layout col=lane&15, row=(lane>>4)*4+i
  int row0 = br * BM + wr * 64 + (lane >> 4) * 4;
  int col0 = bc * BN + wc * 64 + (lane & 15);
#pragma unroll
  for (int m = 0; m < 4; ++m)
#pragma unroll
    for (int n = 0; n < 4; ++n) {
#pragma unroll
      for (int i = 0; i < 4; ++i)
        C[(size_t)(row0 + m * 16 + i) * N + col0 + n * 16] = acc[m][n][i];
    }
}

// ---------------- per-token quantum projection + head-vs-head attention ----------------
// 8 tokens per block, 128 threads. qq staged in LDS (pad +4 floats per row:
// token stride 1028 words -> 8 token-streams land on distinct banks).
__global__ __launch_bounds__(128) void attn_quantum(const float* __restrict__ proj,
                                                    const float* __restrict__ theta,
                                                    ushort* __restrict__ aout) {
  __shared__ float qq[8][1028];
  __shared__ float ct[64];
  int tid = threadIdx.x;
  if (tid < 64) ct[tid] = __cosf(theta[tid]);
  __syncthreads();

  size_t t0 = (size_t)blockIdx.x * 8;
  const float4* p4 = (const float4*)(proj + t0 * NE);

  // phase 1: qq = cos(theta_d) * cos(proj)
  for (int j = tid; j < 8 * NE / 4; j += 128) {
    float4 v = p4[j];
    int t   = j >> 8;            // 256 float4 per token
    int pos = (j & 255) * 4;     // 0..1023, step 4
    int d   = pos & 63;          // wire index (4 consecutive, no wrap)
    float4 o;
    o.x = ct[d + 0] * __cosf(v.x);
    o.y = ct[d + 1] * __cosf(v.y);
    o.z = ct[d + 2] * __cosf(v.z);
    o.w = ct[d + 3] * __cosf(v.w);
    *(float4*)&qq[t][pos] = o;
  }
  __syncthreads();

  // phase 2: one thread per (token, head)
  int t = tid >> 4;   // 0..7
  int h = tid & 15;   // 0..15

  float q[NDK];
#pragma unroll
  for (int d = 0; d < NDK; ++d) q[d] = qq[t][h * NDK + d];

  float sc[NH];
  float mx = -1e30f;
#pragma unroll
  for (int g = 0; g < NH; ++g) {
    float s = 0.f;
#pragma unroll
    for (int d = 0; d < NDK; ++d) s += q[d] * qq[t][g * NDK + d];
    s *= 0.125f;  // 1/sqrt(64)
    sc[g] = s;
    mx = fmaxf(mx, s);
  }
  float sum = 0.f;
#pragma unroll
  for (int g = 0; g < NH; ++g) { sc[g] = __expf(sc[g] - mx); sum += sc[g]; }
  float inv = 1.f / sum;
#pragma unroll
  for (int g = 0; g < NH; ++g) sc[g] *= inv;

  // phase 3: out[t,h,d] = sum_g attn[g] * qq[t][g][d], write bf16 for GEMM2
  ushort* o = aout + (t0 + t) * NE + h * NDK;
#pragma unroll
  for (int d = 0; d < NDK; ++d) {
    float s = 0.f;
#pragma unroll
    for (int g = 0; g < NH; ++g) s += sc[g] * qq[t][g * NDK + d];
    o[d] = f2bf(s);
  }
}

// ---------------- launch ----------------
extern "C" void kernel_launch(void* const* d_in, const int* in_sizes, int n_in,
                              void* d_out, int out_size, void* d_ws, size_t ws_size,
                              hipStream_t stream) {
  const float* x     = (const float*)d_in[0];
  const float* W     = (const float*)d_in[1];
  const float* theta = (const float*)d_in[2];
  float* out = (float*)d_out;

  char* ws = (char*)d_ws;
  ushort* xb   = (ushort*)ws;                                          // 16.7M bf16
  ushort* Wb   = (ushort*)(ws + (size_t)MTOK * NE * 2);                // 1M bf16
  float*  proj = (float*)(ws + (size_t)MTOK * NE * 2 + (size_t)NE * NE * 2); // 16.7M f32
  ushort* aout = xb;  // reuse: xb dead after GEMM1

  cvt_bf16<<<1024, 256, 0, stream>>>(x, xb, MTOK * NE / 4);
  cvt_bf16<<<256, 256, 0, stream>>>(W, Wb, NE * NE / 4);

  dim3 gg(NE / BN, MTOK / BM);  // (8, 128)
  gemm_bt<<<gg, 256, 0, stream>>>(xb, Wb, proj, MTOK, NE, NE);

  attn_quantum<<<MTOK / 8, 128, 0, stream>>>(proj, theta, aout);

  gemm_bt<<<gg, 256, 0, stream>>>(aout, Wb, out, MTOK, NE, NE);
}